// Round 5
// baseline (662.047 us; speedup 1.0000x reference)
//
#include <hip/hip_runtime.h>

// out[co*4+n, ci*4+o, y, x] = sum_{c,ky,kx} k1[co*4+n, ci*4+c, y+ky-7, x+kx-7]
//                                         * k2[co*4+o, ci*4+c, ky, kx]
// MFMA per (co,ci,c,ky):  OUT[y][x] (o=0..3) += sum_u Apad[y+ky][u] * k2[o][ky][u-x]
//   A-frag: lane(y=l&15, kg=l>>4) reads 8 contiguous bf16 (ds_read_b128)
//   B-frag: register Toeplitz via ds_bpermute; src lanes 15..63 zero -> OOB fetches 0.
// Shared-pad plane pairing: two (n,c) planes per padded row
//   [7 zero][15 p0][9 zero][15 p1][10 zero] = 56 shorts (112 B)
//   p0 window u -> col u, p1 window u -> col 24+u. Cross-plane bleed (p0 u=31 hits
//   p1 col 31) is nullified by the B band: w[u-x] = 0 whenever u-x > 14.
// Arena 25984 B -> 6 blocks/CU (24 waves). 4 waves = 4 input channels c.

typedef float f32x4 __attribute__((ext_vector_type(4)));
typedef __bf16 bf16x8 __attribute__((ext_vector_type(8)));

#define KS 15
#define SP 225
#define NCH 256
#define PSTRIDE 56            // shorts per plane-PAIR row
#define GSTRIDE (29 * 56)     // shorts per pair-group (29 rows)

__device__ __forceinline__ unsigned short f2bf(float f) {
    unsigned u = __builtin_bit_cast(unsigned, f);
    u += 0x7FFFu + ((u >> 16) & 1u);   // RNE (finite normals)
    return (unsigned short)(u >> 16);
}

__global__ __launch_bounds__(256, 6)
void blade_conv_mfma(const float* __restrict__ k1,
                     const float* __restrict__ k2,
                     float* __restrict__ out) {
    // phase 1: Apad bf16 [8 pair-groups][29 rows][56 cols] = 25984 B
    // phase 2: slabs f32 [4 wid][4 o][16 x][20 y]          = 20480 B (overlaid)
    __shared__ __align__(16) unsigned char arena[8 * GSTRIDE * 2];
    unsigned short* Apad  = (unsigned short*)arena;
    float*          slabs = (float*)arena;

    const int tid  = threadIdx.x;
    const int lane = tid & 63;
    const int wid  = tid >> 6;            // wave id == input channel c
    const int co = blockIdx.x, ci = blockIdx.y;

    // ---- k2 loads FIRST: latency overlaps zero+stage ----
    float b0[15], b1[15], b2[15], b3[15];
    {
        const size_t base = ((size_t)(co * 4) * NCH + ci * 4 + wid) * SP;
        #pragma unroll
        for (int ky = 0; ky < 15; ++ky) {
            b0[ky] = 0.f; b1[ky] = 0.f; b2[ky] = 0.f; b3[ky] = 0.f;
            if (lane < 15) {
                int p = ky * KS + lane;
                b0[ky] = k2[base + 0 * NCH * SP + p];
                b1[ky] = k2[base + 1 * NCH * SP + p];
                b2[ky] = k2[base + 2 * NCH * SP + p];
                b3[ky] = k2[base + 3 * NCH * SP + p];
            }
        }
    }

    // ---- zero padded A buffer (8*29*56*2 B = 1624 f32x4) ----
    f32x4 z = {0.f, 0.f, 0.f, 0.f};
    for (int i = tid; i < 1624; i += 256) ((f32x4*)arena)[i] = z;
    __syncthreads();

    // ---- stage k1 slice -> Apad (bf16, shared-pad pair layout) ----
    for (int idx = tid; idx < 16 * SP; idx += 256) {
        int nc = idx / SP, rem = idx % SP;
        int y = rem / KS, x = rem % KS;
        int n = nc >> 2, c = nc & 3;
        float v = k1[((size_t)((co * 4 + n) * NCH + ci * 4 + c)) * SP + rem];
        int q = nc >> 1, s = nc & 1;
        Apad[q * GSTRIDE + (y + 7) * PSTRIDE + (s ? 31 : 7) + x] = f2bf(v);
    }

    // ---- pack k2 -> per-lane bpermute sources (lanes 15..63 zero) ----
    int srcA[15], srcB[15];
    #pragma unroll
    for (int ky = 0; ky < 15; ++ky) {
        srcA[ky] = (int)((unsigned)f2bf(b0[ky]) | ((unsigned)f2bf(b1[ky]) << 16));
        srcB[ky] = (int)((unsigned)f2bf(b2[ky]) | ((unsigned)f2bf(b3[ky]) << 16));
    }
    __syncthreads();

    // ---- K loop: 15 ky chunks, K=32 (u) each ----
    f32x4 acc[4][4];
    #pragma unroll
    for (int n = 0; n < 4; ++n)
        #pragma unroll
        for (int o = 0; o < 4; ++o)
            acc[n][o] = z;

    const int yl   = lane & 15;        // output y (M); also the consuming x for B
    const int kg   = lane >> 4;        // k-group
    const int u0mx = (kg << 3) - yl;   // u0 - x
    const int scol = (wid & 1) ? 24 : 0;
    const int whalf = wid >> 1;

    #pragma unroll
    for (int ky = 0; ky < 15; ++ky) {
        bf16x8 af[4];
        #pragma unroll
        for (int n = 0; n < 4; ++n) {
            const unsigned short* p =
                &Apad[(n * 2 + whalf) * GSTRIDE + (yl + ky) * PSTRIDE + scol + (kg << 3)];
            af[n] = *(const bf16x8*)p;
        }
        unsigned r0[8], r1[8];
        #pragma unroll
        for (int j = 0; j < 8; ++j) {
            int a4 = (u0mx + j) << 2;
            r0[j] = (unsigned)__builtin_amdgcn_ds_bpermute(a4, srcA[ky]);
            r1[j] = (unsigned)__builtin_amdgcn_ds_bpermute(a4, srcB[ky]);
        }
        union { bf16x8 v; unsigned u[4]; } bo0, bo1, bo2, bo3;
        #pragma unroll
        for (int t = 0; t < 4; ++t) {
            bo0.u[t] = __builtin_amdgcn_perm(r0[2 * t + 1], r0[2 * t], 0x05040100u);
            bo1.u[t] = __builtin_amdgcn_perm(r0[2 * t + 1], r0[2 * t], 0x07060302u);
            bo2.u[t] = __builtin_amdgcn_perm(r1[2 * t + 1], r1[2 * t], 0x05040100u);
            bo3.u[t] = __builtin_amdgcn_perm(r1[2 * t + 1], r1[2 * t], 0x07060302u);
        }
        #pragma unroll
        for (int n = 0; n < 4; ++n) {
            acc[n][0] = __builtin_amdgcn_mfma_f32_16x16x32_bf16(af[n], bo0.v, acc[n][0], 0, 0, 0);
            acc[n][1] = __builtin_amdgcn_mfma_f32_16x16x32_bf16(af[n], bo1.v, acc[n][1], 0, 0, 0);
            acc[n][2] = __builtin_amdgcn_mfma_f32_16x16x32_bf16(af[n], bo2.v, acc[n][2], 0, 0, 0);
            acc[n][3] = __builtin_amdgcn_mfma_f32_16x16x32_bf16(af[n], bo3.v, acc[n][3], 0, 0, 0);
        }
    }

    // ---- cross-wave (c) reduction: 4 rounds, 4 (o) tiles each (n = round) ----
    const int xl = lane & 15;
    #pragma unroll
    for (int g = 0; g < 4; ++g) {
        __syncthreads();   // g=0: Apad reads done; g>0: prev readout done
        {
            float* slab = slabs + wid * 1280;   // [4 o][16 x][20 y]
            #pragma unroll
            for (int o = 0; o < 4; ++o)
                *(f32x4*)&slab[(o * 16 + xl) * 20 + (kg << 2)] = acc[g][o];
        }
        __syncthreads();
        for (int idx = tid; idx < 4 * SP; idx += 256) {
            int o = idx / SP, rem = idx % SP;
            int yy = rem / KS, xx = rem % KS;
            int soff = (o * 16 + xx) * 20 + yy;
            float s = slabs[soff] + slabs[1280 + soff]
                    + slabs[2560 + soff] + slabs[3840 + soff];
            out[((size_t)((co * 4 + g) * NCH + ci * 4 + o)) * SP + rem] = s;
        }
    }
}

extern "C" void kernel_launch(void* const* d_in, const int* in_sizes, int n_in,
                              void* d_out, int out_size, void* d_ws, size_t ws_size,
                              hipStream_t stream) {
    (void)in_sizes; (void)n_in; (void)d_ws; (void)ws_size; (void)out_size;
    const float* k1 = (const float*)d_in[0];
    const float* k2 = (const float*)d_in[1];
    float* out = (float*)d_out;

    dim3 grid(64, 64, 1);
    dim3 block(256, 1, 1);
    hipLaunchKernelGGL(blade_conv_mfma, grid, block, 0, stream, k1, k2, out);
}

// Round 6
// 86.675 us; speedup vs baseline: 7.6383x; 7.6383x over previous
//
#include <hip/hip_runtime.h>

// out[co*4+n, ci*4+o, y, x] = sum_{c,ky,kx} k1[co*4+n, ci*4+c, y+ky-7, x+kx-7]
//                                         * k2[co*4+o, ci*4+c, ky, kx]
// MFMA per (co,ci,c,ky):  OUT[y][x] (o=0..3) += sum_u Apad[y+ky][u] * k2[o][ky][u-x]
//   A-frag: lane(y=l&15, kg=l>>4) reads 8 contiguous bf16 (ds_read_b128)
//   B-frag: register Toeplitz via ds_bpermute; src lanes 15..63 zero -> OOB fetches 0.
// Shared-pad plane pairing: two (n,c) planes per padded row
//   [7 zero][15 p0][9 zero][15 p1][10 zero] = 56 shorts (112 B)
//   Cross-plane bleed is nullified by the B zero band (w[u-x]=0 for u-x>14).
// Arena 25984 B -> 6 blocks/CU. launch_bounds(256,4): known-good codegen (64 VGPR,
// no spill) — bounds=6 in R5 forced an ~85-reg cap and spilled (FETCH 70->860 MB).

typedef float f32x4 __attribute__((ext_vector_type(4)));
typedef __bf16 bf16x8 __attribute__((ext_vector_type(8)));

#define KS 15
#define SP 225
#define NCH 256
#define PSTRIDE 56            // shorts per plane-PAIR row
#define GSTRIDE (29 * 56)     // shorts per pair-group (29 rows)

__device__ __forceinline__ unsigned short f2bf(float f) {
    unsigned u = __builtin_bit_cast(unsigned, f);
    u += 0x7FFFu + ((u >> 16) & 1u);   // RNE (finite normals)
    return (unsigned short)(u >> 16);
}

__global__ __launch_bounds__(256, 4)
void blade_conv_mfma(const float* __restrict__ k1,
                     const float* __restrict__ k2,
                     float* __restrict__ out) {
    // phase 1: Apad bf16 [8 pair-groups][29 rows][56 cols] = 25984 B
    // phase 2: slabs f32 [4 wid][4 o][16 x][20 y]          = 20480 B (overlaid)
    __shared__ __align__(16) unsigned char arena[8 * GSTRIDE * 2];
    unsigned short* Apad  = (unsigned short*)arena;
    float*          slabs = (float*)arena;

    const int tid  = threadIdx.x;
    const int lane = tid & 63;
    const int wid  = tid >> 6;            // wave id == input channel c
    const int co = blockIdx.x, ci = blockIdx.y;

    // ---- k2 loads FIRST: latency overlaps zero+stage ----
    float b0[15], b1[15], b2[15], b3[15];
    {
        const size_t base = ((size_t)(co * 4) * NCH + ci * 4 + wid) * SP;
        #pragma unroll
        for (int ky = 0; ky < 15; ++ky) {
            b0[ky] = 0.f; b1[ky] = 0.f; b2[ky] = 0.f; b3[ky] = 0.f;
            if (lane < 15) {
                int p = ky * KS + lane;
                b0[ky] = k2[base + 0 * NCH * SP + p];
                b1[ky] = k2[base + 1 * NCH * SP + p];
                b2[ky] = k2[base + 2 * NCH * SP + p];
                b3[ky] = k2[base + 3 * NCH * SP + p];
            }
        }
    }

    // ---- zero padded A buffer (8*29*56*2 B = 1624 f32x4) ----
    f32x4 z = {0.f, 0.f, 0.f, 0.f};
    for (int i = tid; i < 1624; i += 256) ((f32x4*)arena)[i] = z;
    __syncthreads();

    // ---- stage k1 slice -> Apad (bf16, shared-pad pair layout) ----
    for (int idx = tid; idx < 16 * SP; idx += 256) {
        int nc = idx / SP, rem = idx % SP;
        int y = rem / KS, x = rem % KS;
        int n = nc >> 2, c = nc & 3;
        float v = k1[((size_t)((co * 4 + n) * NCH + ci * 4 + c)) * SP + rem];
        int q = nc >> 1, s = nc & 1;
        Apad[q * GSTRIDE + (y + 7) * PSTRIDE + (s ? 31 : 7) + x] = f2bf(v);
    }

    // ---- pack k2 -> per-lane bpermute sources (lanes 15..63 zero) ----
    int srcA[15], srcB[15];
    #pragma unroll
    for (int ky = 0; ky < 15; ++ky) {
        srcA[ky] = (int)((unsigned)f2bf(b0[ky]) | ((unsigned)f2bf(b1[ky]) << 16));
        srcB[ky] = (int)((unsigned)f2bf(b2[ky]) | ((unsigned)f2bf(b3[ky]) << 16));
    }
    __syncthreads();

    // ---- K loop: 15 ky chunks, K=32 (u) each ----
    f32x4 acc[4][4];
    #pragma unroll
    for (int n = 0; n < 4; ++n)
        #pragma unroll
        for (int o = 0; o < 4; ++o)
            acc[n][o] = z;

    const int yl   = lane & 15;        // output y (M); also the consuming x for B
    const int kg   = lane >> 4;        // k-group
    const int u0mx = (kg << 3) - yl;   // u0 - x
    const int scol = (wid & 1) ? 24 : 0;
    const int whalf = wid >> 1;

    #pragma unroll
    for (int ky = 0; ky < 15; ++ky) {
        bf16x8 af[4];
        #pragma unroll
        for (int n = 0; n < 4; ++n) {
            const unsigned short* p =
                &Apad[(n * 2 + whalf) * GSTRIDE + (yl + ky) * PSTRIDE + scol + (kg << 3)];
            af[n] = *(const bf16x8*)p;
        }
        unsigned r0[8], r1[8];
        #pragma unroll
        for (int j = 0; j < 8; ++j) {
            int a4 = (u0mx + j) << 2;
            r0[j] = (unsigned)__builtin_amdgcn_ds_bpermute(a4, srcA[ky]);
            r1[j] = (unsigned)__builtin_amdgcn_ds_bpermute(a4, srcB[ky]);
        }
        union { bf16x8 v; unsigned u[4]; } bo0, bo1, bo2, bo3;
        #pragma unroll
        for (int t = 0; t < 4; ++t) {
            bo0.u[t] = __builtin_amdgcn_perm(r0[2 * t + 1], r0[2 * t], 0x05040100u);
            bo1.u[t] = __builtin_amdgcn_perm(r0[2 * t + 1], r0[2 * t], 0x07060302u);
            bo2.u[t] = __builtin_amdgcn_perm(r1[2 * t + 1], r1[2 * t], 0x05040100u);
            bo3.u[t] = __builtin_amdgcn_perm(r1[2 * t + 1], r1[2 * t], 0x07060302u);
        }
        #pragma unroll
        for (int n = 0; n < 4; ++n) {
            acc[n][0] = __builtin_amdgcn_mfma_f32_16x16x32_bf16(af[n], bo0.v, acc[n][0], 0, 0, 0);
            acc[n][1] = __builtin_amdgcn_mfma_f32_16x16x32_bf16(af[n], bo1.v, acc[n][1], 0, 0, 0);
            acc[n][2] = __builtin_amdgcn_mfma_f32_16x16x32_bf16(af[n], bo2.v, acc[n][2], 0, 0, 0);
            acc[n][3] = __builtin_amdgcn_mfma_f32_16x16x32_bf16(af[n], bo3.v, acc[n][3], 0, 0, 0);
        }
    }

    // ---- cross-wave (c) reduction: 4 rounds, 4 (o) tiles each (n = round) ----
    const int xl = lane & 15;
    #pragma unroll
    for (int g = 0; g < 4; ++g) {
        __syncthreads();   // g=0: Apad reads done; g>0: prev readout done
        {
            float* slab = slabs + wid * 1280;   // [4 o][16 x][20 y]
            #pragma unroll
            for (int o = 0; o < 4; ++o)
                *(f32x4*)&slab[(o * 16 + xl) * 20 + (kg << 2)] = acc[g][o];
        }
        __syncthreads();
        for (int idx = tid; idx < 4 * SP; idx += 256) {
            int o = idx / SP, rem = idx % SP;
            int yy = rem / KS, xx = rem % KS;
            int soff = (o * 16 + xx) * 20 + yy;
            float s = slabs[soff] + slabs[1280 + soff]
                    + slabs[2560 + soff] + slabs[3840 + soff];
            out[((size_t)((co * 4 + g) * NCH + ci * 4 + o)) * SP + rem] = s;
        }
    }
}

extern "C" void kernel_launch(void* const* d_in, const int* in_sizes, int n_in,
                              void* d_out, int out_size, void* d_ws, size_t ws_size,
                              hipStream_t stream) {
    (void)in_sizes; (void)n_in; (void)d_ws; (void)ws_size; (void)out_size;
    const float* k1 = (const float*)d_in[0];
    const float* k2 = (const float*)d_in[1];
    float* out = (float*)d_out;

    dim3 grid(64, 64, 1);
    dim3 block(256, 1, 1);
    hipLaunchKernelGGL(blade_conv_mfma, grid, block, 0, stream, k1, k2, out);
}

// Round 7
// 77.522 us; speedup vs baseline: 8.5401x; 1.1181x over previous
//
#include <hip/hip_runtime.h>

// out[co*4+n, ci*4+o, y, x] = sum_{c,ky,kx} k1[co*4+n, ci*4+c, y+ky-7, x+kx-7]
//                                         * k2[co*4+o, ci*4+c, ky, kx]
// MFMA per (co,ci,c,ky):  OUT[y][x] (o=0..3) += sum_u Apad[y+ky][u] * k2[o][ky][u-x]
//   A-frag: lane(y=l&15, kg=l>>4) reads 8 contiguous bf16 (ds_read_b128)
//   B-frag: 8x ds_read_b64 from an o-interleaved zero-padded Toeplitz table
//           (unit[kx] = {o0,o1,o2,o3} bf16). Row stride 32 units: lane window
//           kx in [kg*8-x, +7] -> slots [32ky, 32ky+46]; next row data at
//           32ky+47 -> OOB kx reads true zeros. Replaces 16 bpermutes/iter.
// Apad 2-D shared-pad tiling: 8 vertical bands (stride 22 rows: bottom zeros
//   of band i = top zeros of band i+1) x 2 horizontal (cols 0/24). Only the
//   DISCARDED yl=15 output row ever reads a neighbor's data.
// Arena 20496 (Apad) + 15872 (table) = 36368 B -> 4 blocks/CU.
// Occupancy is reg-capped (~64 VGPR + 64 AGPR acc = 128/wave -> 4 waves/SIMD).

typedef float f32x4 __attribute__((ext_vector_type(4)));
typedef __bf16 bf16x8 __attribute__((ext_vector_type(8)));

#define KS 15
#define SP 225
#define NCH 256
#define RSTRIDE 56                    // shorts per Apad row
#define ROWS 183                      // 22*7 + 29
#define APAD_SHORTS (ROWS * RSTRIDE)  // 10248 shorts = 20496 B
#define TBL_OFF (APAD_SHORTS * 2)     // byte offset of table (16B aligned)
#define TBL_UPC 496                   // table units (8B) per input channel c
#define ARENA_B (TBL_OFF + 4 * TBL_UPC * 8)   // 36368 B

__device__ __forceinline__ unsigned short f2bf(float f) {
    unsigned u = __builtin_bit_cast(unsigned, f);
    u += 0x7FFFu + ((u >> 16) & 1u);   // RNE (finite normals)
    return (unsigned short)(u >> 16);
}

__global__ __launch_bounds__(256, 4)
void blade_conv_mfma(const float* __restrict__ k1,
                     const float* __restrict__ k2,
                     float* __restrict__ out) {
    // phase 1: Apad bf16 [183 rows][56 cols] + Toeplitz tbl [4c][496 u64]
    // phase 2: slabs f32 [4 wid][4 o][16 x][20 y] = 20480 B (overlays Apad only)
    __shared__ __align__(16) unsigned char arena[ARENA_B];
    unsigned short*     Apad  = (unsigned short*)arena;
    unsigned long long* tbl   = (unsigned long long*)(arena + TBL_OFF);
    float*              slabs = (float*)arena;

    const int tid  = threadIdx.x;
    const int lane = tid & 63;
    const int wid  = tid >> 6;            // wave id == input channel c
    const int co = blockIdx.x, ci = blockIdx.y;

    // ---- zero whole arena (36368/16 = 2273 f32x4) ----
    f32x4 z = {0.f, 0.f, 0.f, 0.f};
    for (int i = tid; i < ARENA_B / 16; i += 256) ((f32x4*)arena)[i] = z;
    __syncthreads();

    // ---- stage k1 -> Apad (bf16, 2-D shared-pad layout) ----
    for (int idx = tid; idx < 16 * SP; idx += 256) {
        int nc = idx / SP, rem = idx % SP;
        int y = rem / KS, x = rem % KS;
        int n = nc >> 2, c = nc & 3;
        float v = k1[((size_t)((co * 4 + n) * NCH + ci * 4 + c)) * SP + rem];
        int band = n * 2 + (c >> 1), side = c & 1;
        Apad[(band * 22 + 7 + y) * RSTRIDE + side * 24 + 7 + x] = f2bf(v);
    }

    // ---- stage k2 -> o-interleaved Toeplitz table ----
    for (int idx = tid; idx < 4 * SP; idx += 256) {
        int c = idx / SP, rem = idx % SP;
        int ky = rem / KS, kx = rem % KS;
        size_t base = ((size_t)(co * 4) * NCH + ci * 4 + c) * SP + rem;  // o=0
        float v0 = k2[base];
        float v1 = k2[base + (size_t)NCH * SP];
        float v2 = k2[base + 2 * (size_t)NCH * SP];
        float v3 = k2[base + 3 * (size_t)NCH * SP];
        unsigned lo = (unsigned)f2bf(v0) | ((unsigned)f2bf(v1) << 16);
        unsigned hi = (unsigned)f2bf(v2) | ((unsigned)f2bf(v3) << 16);
        tbl[c * TBL_UPC + 32 * ky + kx + 15] =
            (unsigned long long)lo | ((unsigned long long)hi << 32);
    }
    __syncthreads();

    // ---- K loop: 15 ky chunks, K=32 (u) each ----
    f32x4 acc[4][4];
    #pragma unroll
    for (int n = 0; n < 4; ++n)
        #pragma unroll
        for (int o = 0; o < 4; ++o)
            acc[n][o] = z;

    const int yl    = lane & 15;       // output y (M); also consuming x for B
    const int kg    = lane >> 4;       // k-group
    const int side_w = wid & 1, whalf = wid >> 1;
    const int acol  = side_w * 24 + (kg << 3);
    const unsigned long long* tbase =
        &tbl[wid * TBL_UPC + (kg << 3) - yl + 15];

    #pragma unroll
    for (int ky = 0; ky < 15; ++ky) {
        bf16x8 af[4];
        #pragma unroll
        for (int n = 0; n < 4; ++n) {
            int band = n * 2 + whalf;
            af[n] = *(const bf16x8*)&Apad[(band * 22 + yl + ky) * RSTRIDE + acol];
        }
        unsigned long long q[8];
        #pragma unroll
        for (int j = 0; j < 8; ++j) q[j] = tbase[32 * ky + j];

        union { bf16x8 v; unsigned u[4]; } bo0, bo1, bo2, bo3;
        #pragma unroll
        for (int t = 0; t < 4; ++t) {
            unsigned a0 = (unsigned)q[2 * t],         a1 = (unsigned)q[2 * t + 1];
            unsigned b0 = (unsigned)(q[2 * t] >> 32), b1 = (unsigned)(q[2 * t + 1] >> 32);
            bo0.u[t] = __builtin_amdgcn_perm(a1, a0, 0x05040100u);
            bo1.u[t] = __builtin_amdgcn_perm(a1, a0, 0x07060302u);
            bo2.u[t] = __builtin_amdgcn_perm(b1, b0, 0x05040100u);
            bo3.u[t] = __builtin_amdgcn_perm(b1, b0, 0x07060302u);
        }
        #pragma unroll
        for (int n = 0; n < 4; ++n) {
            acc[n][0] = __builtin_amdgcn_mfma_f32_16x16x32_bf16(af[n], bo0.v, acc[n][0], 0, 0, 0);
            acc[n][1] = __builtin_amdgcn_mfma_f32_16x16x32_bf16(af[n], bo1.v, acc[n][1], 0, 0, 0);
            acc[n][2] = __builtin_amdgcn_mfma_f32_16x16x32_bf16(af[n], bo2.v, acc[n][2], 0, 0, 0);
            acc[n][3] = __builtin_amdgcn_mfma_f32_16x16x32_bf16(af[n], bo3.v, acc[n][3], 0, 0, 0);
        }
    }

    // ---- cross-wave (c) reduction: 4 rounds, 4 (o) tiles each (n = round) ----
    const int xl = lane & 15;
    #pragma unroll
    for (int g = 0; g < 4; ++g) {
        __syncthreads();   // g=0: Apad reads done; g>0: prev readout done
        {
            float* slab = slabs + wid * 1280;   // [4 o][16 x][20 y]
            #pragma unroll
            for (int o = 0; o < 4; ++o)
                *(f32x4*)&slab[(o * 16 + xl) * 20 + (kg << 2)] = acc[g][o];
        }
        __syncthreads();
        for (int idx = tid; idx < 4 * SP; idx += 256) {
            int o = idx / SP, rem = idx % SP;
            int yy = rem / KS, xx = rem % KS;
            int soff = (o * 16 + xx) * 20 + yy;
            float s = slabs[soff] + slabs[1280 + soff]
                    + slabs[2560 + soff] + slabs[3840 + soff];
            out[((size_t)((co * 4 + g) * NCH + ci * 4 + o)) * SP + rem] = s;
        }
    }
}

extern "C" void kernel_launch(void* const* d_in, const int* in_sizes, int n_in,
                              void* d_out, int out_size, void* d_ws, size_t ws_size,
                              hipStream_t stream) {
    (void)in_sizes; (void)n_in; (void)d_ws; (void)ws_size; (void)out_size;
    const float* k1 = (const float*)d_in[0];
    const float* k2 = (const float*)d_in[1];
    float* out = (float*)d_out;

    dim3 grid(64, 64, 1);
    dim3 block(256, 1, 1);
    hipLaunchKernelGGL(blade_conv_mfma, grid, block, 0, stream, k1, k2, out);
}